// Round 3
// baseline (689.977 us; speedup 1.0000x reference)
//
#include <hip/hip_runtime.h>
#include <hip/hip_bf16.h>

#define BB 4
#define LL 2048
#define HH 8
#define EE 64
#define SK 40
#define NT 40
#define BH (BB*HH)
#define NCH 32
#define CLEN (LL/NCH)   // 64

// ---------------- Kernel 1: sparsity = max_s(q.k_samp) - mean_s(q.k_samp) ----------------
// one wave per (b,h,l); lane = e
__global__ __launch_bounds__(256) void k_spars(const float* __restrict__ q,
                                               const float* __restrict__ k,
                                               const int* __restrict__ samp,
                                               float* __restrict__ spars)
{
    int wid  = (blockIdx.x * blockDim.x + threadIdx.x) >> 6;
    int lane = threadIdx.x & 63;
    int bh = wid / LL;
    int l  = wid - bh * LL;
    int b = bh >> 3, h = bh & 7;

    float qe = q[((size_t)(b*LL + l)*HH + h)*EE + lane];
    float m = -1e30f, s = 0.f;
    for (int si = 0; si < SK; ++si) {
        int idx = samp[l*SK + si];
        float kv = k[((size_t)(b*LL + idx)*HH + h)*EE + lane];
        float p = qe * kv;
        #pragma unroll
        for (int off = 32; off; off >>= 1) p += __shfl_xor(p, off, 64);
        m = fmaxf(m, p);
        s += p;
    }
    if (lane == 0) spars[bh*LL + l] = m - s * (1.0f/SK);
}

// ---------------- Kernel 2: per-(b,h) top-40 (value desc, index asc tie-break) + sel map ----
__global__ __launch_bounds__(256) void k_topk(const float* __restrict__ spars,
                                              int* __restrict__ topidx,
                                              int* __restrict__ sel)
{
    __shared__ float vals[LL];
    __shared__ float rv[256];
    __shared__ int   ri[256];
    __shared__ int   top[NT];
    int bh = blockIdx.x, t = threadIdx.x;

    for (int l = t; l < LL; l += 256) vals[l] = spars[bh*LL + l];
    __syncthreads();

    for (int n = 0; n < NT; ++n) {
        float bv = -3e38f; int bi = LL;
        for (int l = t; l < LL; l += 256) {
            float vv = vals[l];
            if (vv > bv) { bv = vv; bi = l; }   // within-thread l increases, strict > keeps lowest idx
        }
        rv[t] = bv; ri[t] = bi;
        __syncthreads();
        for (int s2 = 128; s2; s2 >>= 1) {
            if (t < s2) {
                float ov = rv[t+s2]; int oi = ri[t+s2];
                if (ov > rv[t] || (ov == rv[t] && oi < ri[t])) { rv[t] = ov; ri[t] = oi; }
            }
            __syncthreads();
        }
        if (t == 0) {
            int bidx = ri[0];
            top[n] = bidx;
            topidx[bh*NT + n] = bidx;
            vals[bidx] = -3e38f;
        }
        __syncthreads();
    }

    for (int l = t; l < LL; l += 256) sel[bh*LL + l] = -1;
    __syncthreads();
    if (t < NT) sel[bh*LL + top[t]] = t;
}

// ---------------- Kernel 3: causal attention for each selected query row -------------------
// one block (4 waves) per (b,h,n); lane = e
__global__ __launch_bounds__(256) void k_attn(const float* __restrict__ q,
                                              const float* __restrict__ k,
                                              const float* __restrict__ v,
                                              const int* __restrict__ topidx,
                                              float* __restrict__ upd)
{
    __shared__ float sc[LL];
    __shared__ float red[256];
    __shared__ float part[4][EE];
    int bh = blockIdx.x / NT, n = blockIdx.x % NT;
    int b = bh >> 3, h = bh & 7;
    int ti = topidx[bh*NT + n];
    int t = threadIdx.x, w = t >> 6, lane = t & 63;
    const float scale = 0.125f;  // 1/sqrt(64)

    float qe = q[((size_t)(b*LL + ti)*HH + h)*EE + lane];

    // scores for j in [0, ti]
    for (int j = w; j <= ti; j += 4) {
        float kv = k[((size_t)(b*LL + j)*HH + h)*EE + lane];
        float p = qe * kv;
        #pragma unroll
        for (int off = 32; off; off >>= 1) p += __shfl_xor(p, off, 64);
        if (lane == 0) sc[j] = p * scale;
    }
    __syncthreads();

    // block max
    float m = -1e30f;
    for (int j = t; j <= ti; j += 256) m = fmaxf(m, sc[j]);
    red[t] = m; __syncthreads();
    for (int s2 = 128; s2; s2 >>= 1) {
        if (t < s2) red[t] = fmaxf(red[t], red[t+s2]);
        __syncthreads();
    }
    m = red[0];
    __syncthreads();

    // exp + sum
    float ssum = 0.f;
    for (int j = t; j <= ti; j += 256) { float p = __expf(sc[j] - m); sc[j] = p; ssum += p; }
    red[t] = ssum; __syncthreads();
    for (int s2 = 128; s2; s2 >>= 1) {
        if (t < s2) red[t] += red[t+s2];
        __syncthreads();
    }
    float inv = 1.0f / red[0];

    // PV
    float acc = 0.f;
    for (int j = w; j <= ti; j += 4)
        acc += sc[j] * v[((size_t)(b*LL + j)*HH + h)*EE + lane];
    part[w][lane] = acc;
    __syncthreads();
    if (w == 0) {
        float r = (part[0][lane] + part[1][lane] + part[2][lane] + part[3][lane]) * inv;
        upd[((size_t)bh*NT + n)*EE + lane] = r;
    }
}

// ---------------- Kernel 4a: per-chunk sums of v over L ------------------------------------
// one wave per (b,h,chunk); lane = e
__global__ __launch_bounds__(256) void k_csum(const float* __restrict__ v,
                                              float* __restrict__ csum)
{
    int wid  = (blockIdx.x * blockDim.x + threadIdx.x) >> 6;
    int lane = threadIdx.x & 63;
    int bh = wid / NCH, c = wid - bh*NCH;
    int b = bh >> 3, h = bh & 7;
    int l0 = c * CLEN;
    float s = 0.f;
    for (int i = 0; i < CLEN; ++i)
        s += v[((size_t)(b*LL + l0 + i)*HH + h)*EE + lane];
    csum[(size_t)wid*EE + lane] = s;
}

// ---------------- Kernel 4b: cumsum + scatter updates + write out --------------------------
__global__ __launch_bounds__(256) void k_out(const float* __restrict__ v,
                                             const float* __restrict__ csum,
                                             const int* __restrict__ sel,
                                             const float* __restrict__ upd,
                                             float* __restrict__ out)
{
    int wid  = (blockIdx.x * blockDim.x + threadIdx.x) >> 6;
    int lane = threadIdx.x & 63;
    int bh = wid / NCH, c = wid - bh*NCH;
    int b = bh >> 3, h = bh & 7;

    float run = 0.f;
    for (int c2 = 0; c2 < c; ++c2) run += csum[((size_t)bh*NCH + c2)*EE + lane];

    int l0 = c * CLEN;
    for (int i = 0; i < CLEN; ++i) {
        int l = l0 + i;
        run += v[((size_t)(b*LL + l)*HH + h)*EE + lane];
        int sn = sel[bh*LL + l];
        float val = (sn >= 0) ? upd[((size_t)bh*NT + sn)*EE + lane] : run;
        out[((size_t)(b*LL + l)*HH + h)*EE + lane] = val;
    }
}

extern "C" void kernel_launch(void* const* d_in, const int* in_sizes, int n_in,
                              void* d_out, int out_size, void* d_ws, size_t ws_size,
                              hipStream_t stream) {
    const float* q = (const float*)d_in[0];
    const float* k = (const float*)d_in[1];
    const float* v = (const float*)d_in[2];
    const int* samp = (const int*)d_in[3];
    float* out = (float*)d_out;

    char* ws = (char*)d_ws;
    float* spars  = (float*)(ws);                                   // 32*2048*4   = 262144
    int*   topidx = (int*)  (ws + 262144);                          // 32*40*4     = 5120 (pad 8192)
    int*   sel    = (int*)  (ws + 262144 + 8192);                   // 32*2048*4   = 262144
    float* upd    = (float*)(ws + 262144 + 8192 + 262144);          // 32*40*64*4  = 327680
    float* csum   = (float*)(ws + 262144 + 8192 + 262144 + 327680); // 32*32*64*4  = 262144

    k_spars<<<BH*LL/4, 256, 0, stream>>>(q, k, samp, spars);
    k_topk <<<BH,      256, 0, stream>>>(spars, topidx, sel);
    k_attn <<<BH*NT,   256, 0, stream>>>(q, k, v, topidx, upd);
    k_csum <<<BH*NCH/4,256, 0, stream>>>(v, csum);
    k_out  <<<BH*NCH/4,256, 0, stream>>>(v, csum, sel, upd, out);
}

// Round 4
// 225.208 us; speedup vs baseline: 3.0637x; 3.0637x over previous
//
#include <hip/hip_runtime.h>
#include <hip/hip_bf16.h>

#define BB 4
#define LL 2048
#define HH 8
#define EE 64
#define SK 40
#define NT 40
#define BH (BB*HH)
#define NCH 128
#define CLEN (LL/NCH)   // 16
#define KS 128          // keys per split (new attn)
#define NS (LL/KS)      // 16 splits

__device__ __forceinline__ size_t ro(int b, int l, int h) {
    return ((size_t)(b*LL + l)*HH + h)*EE;
}
__device__ __forceinline__ float bcast(float x, int sl) {
    return __uint_as_float(__builtin_amdgcn_readlane(__float_as_uint(x), sl));
}

// ---------------- Kernel 1: sparsity = max_s(q.k_samp) - mean_s(q.k_samp) ----------------
// one wave per (b,h,l). f4 gathers: 4 sample-rows per load; LDS-transpose batch reduce.
__global__ __launch_bounds__(256) void k_spars(const float* __restrict__ q,
                                               const float* __restrict__ k,
                                               const int* __restrict__ samp,
                                               float* __restrict__ spars)
{
    __shared__ float pbuf[4][SK][20];   // [wave][sample][16 partials + pad], stride 80B (16B-aligned)
    int wid  = (blockIdx.x * blockDim.x + threadIdx.x) >> 6;
    int lane = threadIdx.x & 63;
    int w    = threadIdx.x >> 6;
    int bh = wid / LL;
    int l  = wid - bh * LL;
    int b = bh >> 3, h = bh & 7;

    int sidx = (lane < SK) ? samp[l*SK + lane] : 0;

    const float4* qrow = (const float4*)(q + ro(b, l, h));
    float4 q4 = qrow[lane & 15];

    int sub = lane >> 4;            // 0..3: which sample within the group of 4
    #pragma unroll
    for (int g = 0; g < SK/4; ++g) {
        int s = 4*g + sub;
        int row = __shfl(sidx, s, 64);
        const float4* kr = (const float4*)(k + ro(b, row, h));
        float4 k4 = kr[lane & 15];
        float p = k4.x*q4.x + k4.y*q4.y + k4.z*q4.z + k4.w*q4.w;
        pbuf[w][s][lane & 15] = p;
    }
    // same-wave LDS RAW: hw keeps per-wave DS order; compiler inserts lgkmcnt for results.
    float dot = 0.f;
    if (lane < SK) {
        const float4* pr = (const float4*)&pbuf[w][lane][0];
        float4 a = pr[0], b4 = pr[1], c4 = pr[2], d4 = pr[3];
        dot = ((a.x+a.y)+(a.z+a.w)) + ((b4.x+b4.y)+(b4.z+b4.w))
            + ((c4.x+c4.y)+(c4.z+c4.w)) + ((d4.x+d4.y)+(d4.z+d4.w));
    }
    float dmax = (lane < SK) ? dot : -INFINITY;
    float dsum = (lane < SK) ? dot : 0.f;
    #pragma unroll
    for (int off = 32; off; off >>= 1) {
        dmax = fmaxf(dmax, __shfl_xor(dmax, off, 64));
        dsum += __shfl_xor(dsum, off, 64);
    }
    if (lane == 0) spars[bh*LL + l] = dmax - dsum * (1.0f/SK);
}

// ---------------- Kernel 2: per-(b,h) top-40 (value desc, index asc tie-break) + sel map ----
// values cached in registers; per pass: 8 reg-cmps + 6-shfl argmax + 4-wave LDS merge.
__global__ __launch_bounds__(256) void k_topk(const float* __restrict__ spars,
                                              int* __restrict__ topidx,
                                              int* __restrict__ sel)
{
    __shared__ float wv[4];
    __shared__ int   wi[4];
    __shared__ int   top[NT];
    int bh = blockIdx.x, t = threadIdx.x, w = t >> 6, lane = t & 63;

    float r[8];
    #pragma unroll
    for (int i = 0; i < 8; ++i) r[i] = spars[bh*LL + i*256 + t];

    for (int n = 0; n < NT; ++n) {
        float bv = r[0]; int bi = t;
        #pragma unroll
        for (int i = 1; i < 8; ++i)
            if (r[i] > bv) { bv = r[i]; bi = i*256 + t; }   // ascending l within thread
        #pragma unroll
        for (int off = 32; off; off >>= 1) {
            float ov = __shfl_xor(bv, off, 64);
            int   oi = __shfl_xor(bi, off, 64);
            if (ov > bv || (ov == bv && oi < bi)) { bv = ov; bi = oi; }
        }
        if (lane == 0) { wv[w] = bv; wi[w] = bi; }
        __syncthreads();
        float gv = wv[0]; int gi = wi[0];
        #pragma unroll
        for (int j = 1; j < 4; ++j) {
            float ov = wv[j]; int oi = wi[j];
            if (ov > gv || (ov == gv && oi < gi)) { gv = ov; gi = oi; }
        }
        if (t == 0) { top[n] = gi; topidx[bh*NT + n] = gi; }
        if ((gi & 255) == t) {               // owner clears its slot (static indices)
            int slot = gi >> 8;
            #pragma unroll
            for (int i = 0; i < 8; ++i) if (i == slot) r[i] = -INFINITY;
        }
        __syncthreads();
    }

    for (int l2 = t; l2 < LL; l2 += 256) sel[bh*LL + l2] = -1;
    __syncthreads();
    if (t < NT) sel[bh*LL + top[t]] = t;
}

// ---------------- Kernel 3a: split-K flash attention; partials per (bh,n,split) ------------
__global__ __launch_bounds__(256) void k_attn_split(const float* __restrict__ q,
                                                    const float* __restrict__ k,
                                                    const float* __restrict__ v,
                                                    const int* __restrict__ topidx,
                                                    float* __restrict__ pm,
                                                    float* __restrict__ pl,
                                                    float* __restrict__ pO)
{
    __shared__ float KT[EE][KS+1];   // transposed, padded: conflict-free both ways
    __shared__ float Vs[KS][EE];
    __shared__ float Qs[NT][EE];
    __shared__ int   tix[NT];
    __shared__ int   maxti_s;
    int bh = blockIdx.x / NS, split = blockIdx.x % NS;
    int b = bh >> 3, h = bh & 7;
    int base = split * KS;
    int t = threadIdx.x, w = t >> 6, lane = t & 63;

    if (t < NT) tix[t] = topidx[bh*NT + t];
    __syncthreads();
    if (t == 0) { int m = 0; for (int i = 0; i < NT; ++i) m = max(m, tix[i]); maxti_s = m; }
    __syncthreads();
    int jmaxAll = min(KS, maxti_s - base + 1);

    // stage Q (scaled): 16 rows/pass, f4
    int rr = t >> 4, c4 = t & 15;
    for (int p = 0; p < 3; ++p) {
        int n = p*16 + rr;
        if (n < NT) {
            const float4* qr = (const float4*)(q + ro(b, tix[n], h));
            float4 x = qr[c4];
            Qs[n][c4*4+0] = x.x*0.125f; Qs[n][c4*4+1] = x.y*0.125f;
            Qs[n][c4*4+2] = x.z*0.125f; Qs[n][c4*4+3] = x.w*0.125f;
        }
    }
    // stage K transposed + V, rows < jmaxAll
    for (int p = 0; p < KS/16; ++p) {
        int kr = p*16 + rr;
        if (kr < jmaxAll) {
            const float4* krow = (const float4*)(k + ro(b, base + kr, h));
            float4 x = krow[c4];
            KT[c4*4+0][kr] = x.x; KT[c4*4+1][kr] = x.y;
            KT[c4*4+2][kr] = x.z; KT[c4*4+3][kr] = x.w;
            const float4* vrow = (const float4*)(v + ro(b, base + kr, h));
            ((float4*)&Vs[kr][0])[c4] = vrow[c4];
        }
    }
    __syncthreads();

    // 5 query-pairs per wave
    for (int jj = 0; jj < 5; ++jj) {
        int na = w + 8*jj, nb = w + 8*jj + 4;
        int ja = min(KS, tix[na] - base + 1);
        int jb = min(KS, tix[nb] - base + 1);
        bool aa = ja > 0, ab = jb > 0;
        size_t pba = ((size_t)(bh*NT + na)*NS + split);
        size_t pbb = ((size_t)(bh*NT + nb)*NS + split);
        int jp = max(ja, jb);
        if (jp <= 0) {
            if (lane == 0) { pm[pba] = -INFINITY; pl[pba] = 0.f; pm[pbb] = -INFINITY; pl[pbb] = 0.f; }
            pO[pba*EE + lane] = 0.f;
            pO[pbb*EE + lane] = 0.f;
            continue;
        }
        float s0a = 0, s1a = 0, s0b = 0, s1b = 0;
        #pragma unroll 4
        for (int e = 0; e < EE; ++e) {
            float k0 = KT[e][lane], k1 = KT[e][64+lane];
            float qa = Qs[na][e],  qb = Qs[nb][e];
            s0a += qa*k0; s1a += qa*k1;
            s0b += qb*k0; s1b += qb*k1;
        }
        s0a = (lane      < ja) ? s0a : -INFINITY;
        s1a = (lane + 64 < ja) ? s1a : -INFINITY;
        s0b = (lane      < jb) ? s0b : -INFINITY;
        s1b = (lane + 64 < jb) ? s1b : -INFINITY;
        float ma = fmaxf(s0a, s1a), mb = fmaxf(s0b, s1b);
        #pragma unroll
        for (int off = 32; off; off >>= 1) {
            ma = fmaxf(ma, __shfl_xor(ma, off, 64));
            mb = fmaxf(mb, __shfl_xor(mb, off, 64));
        }
        float p0a = aa ? __expf(s0a - ma) : 0.f;
        float p1a = aa ? __expf(s1a - ma) : 0.f;
        float p0b = ab ? __expf(s0b - mb) : 0.f;
        float p1b = ab ? __expf(s1b - mb) : 0.f;
        float la = p0a + p1a, lb = p0b + p1b;
        #pragma unroll
        for (int off = 32; off; off >>= 1) {
            la += __shfl_xor(la, off, 64);
            lb += __shfl_xor(lb, off, 64);
        }
        float oa = 0.f, ob = 0.f;
        int lim0 = min(64, jp);
        #pragma unroll 4
        for (int kk = 0; kk < lim0; ++kk) {
            float vv = Vs[kk][lane];
            oa += bcast(p0a, kk) * vv;
            ob += bcast(p0b, kk) * vv;
        }
        int lim1 = min(64, jp - 64);
        #pragma unroll 4
        for (int kk = 0; kk < lim1; ++kk) {
            float vv = Vs[64+kk][lane];
            oa += bcast(p1a, kk) * vv;
            ob += bcast(p1b, kk) * vv;
        }
        if (lane == 0) {
            pm[pba] = aa ? ma : -INFINITY;  pl[pba] = aa ? la : 0.f;
            pm[pbb] = ab ? mb : -INFINITY;  pl[pbb] = ab ? lb : 0.f;
        }
        pO[pba*EE + lane] = aa ? oa : 0.f;
        pO[pbb*EE + lane] = ab ? ob : 0.f;
    }
}

// ---------------- Kernel 3b: combine split partials -> upd ---------------------------------
__global__ __launch_bounds__(256) void k_attn_comb(const float* __restrict__ pm,
                                                   const float* __restrict__ pl,
                                                   const float* __restrict__ pO,
                                                   float* __restrict__ upd)
{
    int wid  = (blockIdx.x * blockDim.x + threadIdx.x) >> 6;   // bh*NT + n
    int lane = threadIdx.x & 63;
    if (wid >= BH*NT) return;
    float M = -INFINITY;
    #pragma unroll
    for (int s = 0; s < NS; ++s) M = fmaxf(M, pm[wid*NS + s]);
    float L = 0.f, O = 0.f;
    #pragma unroll
    for (int s = 0; s < NS; ++s) {
        float ms = pm[wid*NS + s];
        float sc = __expf(ms - M);          // ms=-inf -> 0
        L += pl[wid*NS + s] * sc;
        O += pO[(size_t)(wid*NS + s)*EE + lane] * sc;
    }
    upd[(size_t)wid*EE + lane] = O / L;
}

// ---------------- Kernel 3-fallback: old per-(bh,n) attention (if ws too small) ------------
__global__ __launch_bounds__(256) void k_attn_old(const float* __restrict__ q,
                                                  const float* __restrict__ k,
                                                  const float* __restrict__ v,
                                                  const int* __restrict__ topidx,
                                                  float* __restrict__ upd)
{
    __shared__ float sc[LL];
    __shared__ float red[256];
    __shared__ float part[4][EE];
    int bh = blockIdx.x / NT, n = blockIdx.x % NT;
    int b = bh >> 3, h = bh & 7;
    int ti = topidx[bh*NT + n];
    int t = threadIdx.x, w = t >> 6, lane = t & 63;

    float qe = q[ro(b, ti, h) + lane];
    for (int j = w; j <= ti; j += 4) {
        float kv = k[ro(b, j, h) + lane];
        float p = qe * kv;
        #pragma unroll
        for (int off = 32; off; off >>= 1) p += __shfl_xor(p, off, 64);
        if (lane == 0) sc[j] = p * 0.125f;
    }
    __syncthreads();
    float m = -1e30f;
    for (int j = t; j <= ti; j += 256) m = fmaxf(m, sc[j]);
    red[t] = m; __syncthreads();
    for (int s2 = 128; s2; s2 >>= 1) { if (t < s2) red[t] = fmaxf(red[t], red[t+s2]); __syncthreads(); }
    m = red[0]; __syncthreads();
    float ssum = 0.f;
    for (int j = t; j <= ti; j += 256) { float p = __expf(sc[j] - m); sc[j] = p; ssum += p; }
    red[t] = ssum; __syncthreads();
    for (int s2 = 128; s2; s2 >>= 1) { if (t < s2) red[t] += red[t+s2]; __syncthreads(); }
    float inv = 1.0f / red[0];
    float acc = 0.f;
    for (int j = w; j <= ti; j += 4) acc += sc[j] * v[ro(b, j, h) + lane];
    part[w][lane] = acc;
    __syncthreads();
    if (w == 0) {
        float r = (part[0][lane] + part[1][lane] + part[2][lane] + part[3][lane]) * inv;
        upd[((size_t)bh*NT + n)*EE + lane] = r;
    }
}

// ---------------- Kernel 4a: per-chunk sums of v -------------------------------------------
__global__ __launch_bounds__(256) void k_csum(const float* __restrict__ v,
                                              float* __restrict__ csum)
{
    int wid  = (blockIdx.x * blockDim.x + threadIdx.x) >> 6;
    int lane = threadIdx.x & 63;
    int bh = wid / NCH, c = wid - bh*NCH;
    int b = bh >> 3, h = bh & 7;
    int l0 = c * CLEN;
    float s = 0.f;
    #pragma unroll 4
    for (int i = 0; i < CLEN; ++i)
        s += v[ro(b, l0 + i, h) + lane];
    csum[(size_t)wid*EE + lane] = s;
}

// ---------------- Kernel 4b: in-place exclusive prefix over chunks -------------------------
__global__ __launch_bounds__(256) void k_pfx(float* __restrict__ csum)
{
    int wid  = (blockIdx.x * blockDim.x + threadIdx.x) >> 6;   // bh
    int lane = threadIdx.x & 63;
    if (wid >= BH) return;
    float run = 0.f;
    for (int c = 0; c < NCH; ++c) {
        size_t a = ((size_t)wid*NCH + c)*EE + lane;
        float x = csum[a];
        csum[a] = run;
        run += x;
    }
}

// ---------------- Kernel 4c: cumsum + scatter + write --------------------------------------
__global__ __launch_bounds__(256) void k_out(const float* __restrict__ v,
                                             const float* __restrict__ csum,
                                             const int* __restrict__ sel,
                                             const float* __restrict__ upd,
                                             float* __restrict__ out)
{
    int wid  = (blockIdx.x * blockDim.x + threadIdx.x) >> 6;
    int lane = threadIdx.x & 63;
    int bh = wid / NCH, c = wid - bh*NCH;
    int b = bh >> 3, h = bh & 7;

    float run = csum[((size_t)bh*NCH + c)*EE + lane];   // exclusive prefix
    int l0 = c * CLEN;
    #pragma unroll 4
    for (int i = 0; i < CLEN; ++i) {
        int l = l0 + i;
        run += v[ro(b, l, h) + lane];
        int sn = sel[bh*LL + l];
        float val = (sn >= 0) ? upd[((size_t)bh*NT + sn)*EE + lane] : run;
        out[ro(b, l, h) + lane] = val;
    }
}

extern "C" void kernel_launch(void* const* d_in, const int* in_sizes, int n_in,
                              void* d_out, int out_size, void* d_ws, size_t ws_size,
                              hipStream_t stream) {
    const float* q = (const float*)d_in[0];
    const float* k = (const float*)d_in[1];
    const float* v = (const float*)d_in[2];
    const int* samp = (const int*)d_in[3];
    float* out = (float*)d_out;

    char* ws = (char*)d_ws;
    size_t o = 0;
    float* spars  = (float*)(ws + o); o += (size_t)BH*LL*4;          // 262144
    int*   topidx = (int*)  (ws + o); o += 8192;                     // 1280 used
    int*   sel    = (int*)  (ws + o); o += (size_t)BH*LL*4;          // 262144
    float* upd    = (float*)(ws + o); o += (size_t)BH*NT*EE*4;       // 327680
    float* csum   = (float*)(ws + o); o += (size_t)BH*NCH*EE*4;      // 1048576
    size_t base_need = o;
    float* pm = (float*)(ws + o); o += (size_t)BH*NT*NS*4;           // 81920
    float* pl = (float*)(ws + o); o += (size_t)BH*NT*NS*4;           // 81920
    float* pO = (float*)(ws + o); o += (size_t)BH*NT*NS*EE*4;        // 5242880
    size_t full_need = o;

    k_spars<<<BH*LL/4, 256, 0, stream>>>(q, k, samp, spars);
    k_topk <<<BH,      256, 0, stream>>>(spars, topidx, sel);
    if (ws_size >= full_need) {
        k_attn_split<<<BH*NS, 256, 0, stream>>>(q, k, v, topidx, pm, pl, pO);
        k_attn_comb <<<BH*NT/4, 256, 0, stream>>>(pm, pl, pO, upd);
    } else if (ws_size >= base_need) {
        k_attn_old<<<BH*NT, 256, 0, stream>>>(q, k, v, topidx, upd);
    }
    k_csum<<<BH*NCH/4, 256, 0, stream>>>(v, csum);
    k_pfx <<<(BH+3)/4, 256, 0, stream>>>(csum);
    k_out <<<BH*NCH/4, 256, 0, stream>>>(v, csum, sel, upd, out);
}

// Round 5
// 217.440 us; speedup vs baseline: 3.1732x; 1.0357x over previous
//
#include <hip/hip_runtime.h>
#include <hip/hip_bf16.h>

#define BB 4
#define LL 2048
#define HH 8
#define EE 64
#define SK 40
#define NT 40
#define BH (BB*HH)
#define NCH 128
#define CLEN (LL/NCH)   // 16
#define KS 64           // keys per split
#define NS (LL/KS)      // 32 splits
#define NQW 10          // queries per wave (4 waves * 10 = 40)

__device__ __forceinline__ size_t ro(int b, int l, int h) {
    return ((size_t)(b*LL + l)*HH + h)*EE;
}
__device__ __forceinline__ float bcast(float x, int sl) {
    return __uint_as_float(__builtin_amdgcn_readlane(__float_as_uint(x), sl));
}

// ---------------- Kernel 1: sparsity = max_s(q.k_samp) - mean_s(q.k_samp) ----------------
// one wave per (b,h,l); XCD-swizzled so bh&7 == blockIdx&7 (per-XCD L2 keeps 4 K-slices = 2MB)
__global__ __launch_bounds__(256) void k_spars(const float* __restrict__ q,
                                               const float* __restrict__ k,
                                               const int* __restrict__ samp,
                                               float* __restrict__ spars)
{
    __shared__ float pbuf[4][SK][20];
    int bid = blockIdx.x;
    int w    = threadIdx.x >> 6;
    int lane = threadIdx.x & 63;
    int bh = (((bid >> 3) & 3) << 3) | (bid & 7);
    int l  = (bid >> 5) * 4 + w;
    int b = bh >> 3, h = bh & 7;

    int sidx = (lane < SK) ? samp[l*SK + lane] : 0;

    const float4* qrow = (const float4*)(q + ro(b, l, h));
    float4 q4 = qrow[lane & 15];

    int sub = lane >> 4;
    #pragma unroll
    for (int g = 0; g < SK/4; ++g) {
        int s = 4*g + sub;
        int row = __shfl(sidx, s, 64);
        const float4* kr = (const float4*)(k + ro(b, row, h));
        float4 k4 = kr[lane & 15];
        float p = k4.x*q4.x + k4.y*q4.y + k4.z*q4.z + k4.w*q4.w;
        pbuf[w][s][lane & 15] = p;
    }
    float dot = 0.f;
    if (lane < SK) {
        const float4* pr = (const float4*)&pbuf[w][lane][0];
        float4 a = pr[0], b4 = pr[1], c4 = pr[2], d4 = pr[3];
        dot = ((a.x+a.y)+(a.z+a.w)) + ((b4.x+b4.y)+(b4.z+b4.w))
            + ((c4.x+c4.y)+(c4.z+c4.w)) + ((d4.x+d4.y)+(d4.z+d4.w));
    }
    float dmax = (lane < SK) ? dot : -INFINITY;
    float dsum = (lane < SK) ? dot : 0.f;
    #pragma unroll
    for (int off = 32; off; off >>= 1) {
        dmax = fmaxf(dmax, __shfl_xor(dmax, off, 64));
        dsum += __shfl_xor(dsum, off, 64);
    }
    if (lane == 0) spars[bh*LL + l] = dmax - dsum * (1.0f/SK);
}

// ---------------- Kernel 2: per-(b,h) top-40 + sel map -------------------------------------
__global__ __launch_bounds__(256) void k_topk(const float* __restrict__ spars,
                                              int* __restrict__ topidx,
                                              signed char* __restrict__ sel)
{
    __shared__ float wv[4];
    __shared__ int   wi[4];
    __shared__ int   top[NT];
    int bh = blockIdx.x, t = threadIdx.x, w = t >> 6, lane = t & 63;

    float r[8];
    #pragma unroll
    for (int i = 0; i < 8; ++i) r[i] = spars[bh*LL + i*256 + t];

    for (int n = 0; n < NT; ++n) {
        float bv = r[0]; int bi = t;
        #pragma unroll
        for (int i = 1; i < 8; ++i)
            if (r[i] > bv) { bv = r[i]; bi = i*256 + t; }
        #pragma unroll
        for (int off = 32; off; off >>= 1) {
            float ov = __shfl_xor(bv, off, 64);
            int   oi = __shfl_xor(bi, off, 64);
            if (ov > bv || (ov == bv && oi < bi)) { bv = ov; bi = oi; }
        }
        if (lane == 0) { wv[w] = bv; wi[w] = bi; }
        __syncthreads();
        float gv = wv[0]; int gi = wi[0];
        #pragma unroll
        for (int j = 1; j < 4; ++j) {
            float ov = wv[j]; int oi = wi[j];
            if (ov > gv || (ov == gv && oi < gi)) { gv = ov; gi = oi; }
        }
        if (t == 0) { top[n] = gi; topidx[bh*NT + n] = gi; }
        if ((gi & 255) == t) {
            int slot = gi >> 8;
            #pragma unroll
            for (int i = 0; i < 8; ++i) if (i == slot) r[i] = -INFINITY;
        }
        __syncthreads();
    }

    for (int l2 = t; l2 < LL; l2 += 256) sel[bh*LL + l2] = -1;
    __syncthreads();
    if (t < NT) sel[bh*LL + top[t]] = (signed char)t;
}

// ---------------- Kernel 3a: split-K flash attention, register-tiled -----------------------
// block = (bh, split); 4 waves x 10 queries; KS=64 keys staged in LDS
__global__ __launch_bounds__(256) void k_attn_split(const float* __restrict__ q,
                                                    const float* __restrict__ k,
                                                    const float* __restrict__ v,
                                                    const int* __restrict__ topidx,
                                                    float* __restrict__ pm,
                                                    float* __restrict__ pl,
                                                    __hip_bfloat16* __restrict__ pO)
{
    __shared__ float KT[EE][KS+1];   // transposed, padded: ds_read KT[e][lane] conflict-free
    __shared__ float Vs[KS][EE];     // Vs[kk][lane] conflict-free
    __shared__ int   tix[NT];
    int bh = blockIdx.x >> 5, split = blockIdx.x & 31;
    int b = bh >> 3, h = bh & 7;
    int base = split * KS;
    int t = threadIdx.x, w = t >> 6, lane = t & 63;

    if (t < NT) tix[t] = topidx[bh*NT + t];
    __syncthreads();

    // stage K (transposed) + V
    int rr = t >> 4, c4 = t & 15;
    #pragma unroll
    for (int p = 0; p < 4; ++p) {
        int kr = p*16 + rr;
        const float4* krow = (const float4*)(k + ro(b, base + kr, h));
        float4 x = krow[c4];
        KT[c4*4+0][kr] = x.x; KT[c4*4+1][kr] = x.y;
        KT[c4*4+2][kr] = x.z; KT[c4*4+3][kr] = x.w;
        const float4* vrow = (const float4*)(v + ro(b, base + kr, h));
        ((float4*)&Vs[kr][0])[c4] = vrow[c4];
    }

    // Q into registers (lane = e), scaled
    float qreg[NQW]; int jn[NQW];
    #pragma unroll
    for (int r = 0; r < NQW; ++r) {
        int ti = tix[w*NQW + r];
        jn[r] = min(KS, ti - base + 1);        // may be <= 0 (fully masked)
        qreg[r] = q[ro(b, ti, h) + lane] * 0.125f;
    }
    __syncthreads();

    // QK: lane = key j; S[r] accumulated with Q broadcast via readlane
    float S[NQW];
    #pragma unroll
    for (int r = 0; r < NQW; ++r) S[r] = 0.f;
    for (int e0 = 0; e0 < EE; e0 += 16) {
        #pragma unroll
        for (int j = 0; j < 16; ++j) {
            int e = e0 + j;
            float ke = KT[e][lane];
            #pragma unroll
            for (int r = 0; r < NQW; ++r)
                S[r] = fmaf(ke, bcast(qreg[r], e), S[r]);
        }
    }

    // mask + softmax (lane = key)
    float P[NQW], mloc[NQW], lloc[NQW];
    #pragma unroll
    for (int r = 0; r < NQW; ++r) {
        float s = (lane < jn[r]) ? S[r] : -INFINITY;
        float m = s;
        #pragma unroll
        for (int off = 32; off; off >>= 1) m = fmaxf(m, __shfl_xor(m, off, 64));
        bool act = jn[r] > 0;
        float p = act ? __expf(s - m) : 0.f;    // masked lanes: exp(-inf - finite) = 0
        float ls = p;
        #pragma unroll
        for (int off = 32; off; off >>= 1) ls += __shfl_xor(ls, off, 64);
        P[r] = p; mloc[r] = act ? m : -INFINITY; lloc[r] = act ? ls : 0.f;
    }

    // PV: lane = e; P broadcast via readlane
    float O[NQW];
    #pragma unroll
    for (int r = 0; r < NQW; ++r) O[r] = 0.f;
    for (int k0 = 0; k0 < KS; k0 += 16) {
        #pragma unroll
        for (int j = 0; j < 16; ++j) {
            int kk = k0 + j;
            float ve = Vs[kk][lane];
            #pragma unroll
            for (int r = 0; r < NQW; ++r)
                O[r] = fmaf(ve, bcast(P[r], kk), O[r]);
        }
    }

    // write partials
    #pragma unroll
    for (int r = 0; r < NQW; ++r) {
        int n = w*NQW + r;
        size_t idx = (size_t)(bh*NT + n)*NS + split;
        if (lane == 0) { pm[idx] = mloc[r]; pl[idx] = lloc[r]; }
        pO[idx*EE + lane] = __float2bfloat16(O[r]);
    }
}

// ---------------- Kernel 3b: combine split partials -> upd ---------------------------------
__global__ __launch_bounds__(256) void k_attn_comb(const float* __restrict__ pm,
                                                   const float* __restrict__ pl,
                                                   const __hip_bfloat16* __restrict__ pO,
                                                   float* __restrict__ upd)
{
    int wid  = (blockIdx.x * blockDim.x + threadIdx.x) >> 6;   // bh*NT + n, 1280 waves
    int lane = threadIdx.x & 63;
    float pmv = (lane < NS) ? pm[(size_t)wid*NS + lane] : -INFINITY;
    float plv = (lane < NS) ? pl[(size_t)wid*NS + lane] : 0.f;
    float M = pmv;
    #pragma unroll
    for (int off = 32; off; off >>= 1) M = fmaxf(M, __shfl_xor(M, off, 64));
    float sc = (lane < NS && pmv > -INFINITY) ? __expf(pmv - M) : 0.f;
    float L = plv * sc;
    #pragma unroll
    for (int off = 32; off; off >>= 1) L += __shfl_xor(L, off, 64);
    float O = 0.f;
    for (int s = 0; s < NS; ++s) {
        float w = bcast(sc, s);
        O += __bfloat162float(pO[((size_t)wid*NS + s)*EE + lane]) * w;
    }
    upd[(size_t)wid*EE + lane] = O / L;
}

// ---------------- Kernel 4a: per-chunk sums of v -------------------------------------------
__global__ __launch_bounds__(256) void k_csum(const float* __restrict__ v,
                                              float* __restrict__ csum)
{
    int wid  = (blockIdx.x * blockDim.x + threadIdx.x) >> 6;
    int lane = threadIdx.x & 63;
    int bh = wid / NCH, c = wid - bh*NCH;
    int b = bh >> 3, h = bh & 7;
    int l0 = c * CLEN;
    float s = 0.f;
    #pragma unroll 4
    for (int i = 0; i < CLEN; ++i)
        s += v[ro(b, l0 + i, h) + lane];
    csum[(size_t)wid*EE + lane] = s;
}

// ---------------- Kernel 4b: per-bh exclusive prefix over chunks (LDS scan) ----------------
__global__ __launch_bounds__(256) void k_pfx(float* __restrict__ csum)
{
    __shared__ float buf[NCH*EE];    // 32 KB
    __shared__ float gs[4*EE];
    int bh = blockIdx.x, t = threadIdx.x;
    int e = t & 63, g = t >> 6;

    for (int i = t; i < NCH*EE; i += 256) buf[i] = csum[(size_t)bh*NCH*EE + i];
    __syncthreads();

    float s = 0.f;
    for (int c = g*32; c < g*32+32; ++c) s += buf[c*EE + e];
    gs[g*EE + e] = s;
    __syncthreads();

    float run = 0.f;
    for (int j = 0; j < g; ++j) run += gs[j*EE + e];
    for (int c = g*32; c < g*32+32; ++c) {
        float x = buf[c*EE + e];
        buf[c*EE + e] = run;
        run += x;
    }
    __syncthreads();

    for (int i = t; i < NCH*EE; i += 256) csum[(size_t)bh*NCH*EE + i] = buf[i];
}

// ---------------- Kernel 4c: cumsum + scatter + write --------------------------------------
__global__ __launch_bounds__(256) void k_out(const float* __restrict__ v,
                                             const float* __restrict__ csum,
                                             const signed char* __restrict__ sel,
                                             const float* __restrict__ upd,
                                             float* __restrict__ out)
{
    int wid  = (blockIdx.x * blockDim.x + threadIdx.x) >> 6;
    int lane = threadIdx.x & 63;
    int bh = wid / NCH, c = wid - bh*NCH;
    int b = bh >> 3, h = bh & 7;

    float run = csum[((size_t)bh*NCH + c)*EE + lane];   // exclusive prefix
    int l0 = c * CLEN;
    #pragma unroll 4
    for (int i = 0; i < CLEN; ++i) {
        int l = l0 + i;
        run += v[ro(b, l, h) + lane];
        int sn = sel[bh*LL + l];
        float val = (sn >= 0) ? upd[((size_t)bh*NT + sn)*EE + lane] : run;
        out[ro(b, l, h) + lane] = val;
    }
}

// ---------------- Fallback attention (tiny ws) ---------------------------------------------
__global__ __launch_bounds__(256) void k_attn_old(const float* __restrict__ q,
                                                  const float* __restrict__ k,
                                                  const float* __restrict__ v,
                                                  const int* __restrict__ topidx,
                                                  float* __restrict__ upd)
{
    __shared__ float sc[LL];
    __shared__ float red[256];
    __shared__ float part[4][EE];
    int bh = blockIdx.x / NT, n = blockIdx.x % NT;
    int b = bh >> 3, h = bh & 7;
    int ti = topidx[bh*NT + n];
    int t = threadIdx.x, w = t >> 6, lane = t & 63;

    float qe = q[ro(b, ti, h) + lane];
    for (int j = w; j <= ti; j += 4) {
        float kv = k[ro(b, j, h) + lane];
        float p = qe * kv;
        #pragma unroll
        for (int off = 32; off; off >>= 1) p += __shfl_xor(p, off, 64);
        if (lane == 0) sc[j] = p * 0.125f;
    }
    __syncthreads();
    float m = -1e30f;
    for (int j = t; j <= ti; j += 256) m = fmaxf(m, sc[j]);
    red[t] = m; __syncthreads();
    for (int s2 = 128; s2; s2 >>= 1) { if (t < s2) red[t] = fmaxf(red[t], red[t+s2]); __syncthreads(); }
    m = red[0]; __syncthreads();
    float ssum = 0.f;
    for (int j = t; j <= ti; j += 256) { float p = __expf(sc[j] - m); sc[j] = p; ssum += p; }
    red[t] = ssum; __syncthreads();
    for (int s2 = 128; s2; s2 >>= 1) { if (t < s2) red[t] += red[t+s2]; __syncthreads(); }
    float inv = 1.0f / red[0];
    float acc = 0.f;
    for (int j = w; j <= ti; j += 4) acc += sc[j] * v[ro(b, j, h) + lane];
    part[w][lane] = acc;
    __syncthreads();
    if (w == 0) {
        float r = (part[0][lane] + part[1][lane] + part[2][lane] + part[3][lane]) * inv;
        upd[((size_t)bh*NT + n)*EE + lane] = r;
    }
}

extern "C" void kernel_launch(void* const* d_in, const int* in_sizes, int n_in,
                              void* d_out, int out_size, void* d_ws, size_t ws_size,
                              hipStream_t stream) {
    const float* q = (const float*)d_in[0];
    const float* k = (const float*)d_in[1];
    const float* v = (const float*)d_in[2];
    const int* samp = (const int*)d_in[3];
    float* out = (float*)d_out;

    char* ws = (char*)d_ws;
    // layout (with aliasing; stream is serial so lifetimes don't overlap):
    //   [0]       spars (256K)  -- dead after k_topk; pm aliases it (160K)
    //   [256K]    topidx (8K)
    //   [264K]    sel int8 (64K)
    //   [328K]    upd (320K)
    //   [648K]    pl (160K)
    //   [808K]    pO bf16 (5120K) -- dead after k_attn_comb; csum aliases it (1024K)
    float*          spars  = (float*)(ws);
    float*          pm     = (float*)(ws);
    int*            topidx = (int*)  (ws + 262144);
    signed char*    sel    = (signed char*)(ws + 262144 + 8192);
    float*          upd    = (float*)(ws + 262144 + 8192 + 65536);
    float*          pl     = (float*)(ws + 262144 + 8192 + 65536 + 327680);
    char*           pObase =          ws + 262144 + 8192 + 65536 + 327680 + 163840;
    __hip_bfloat16* pO     = (__hip_bfloat16*)pObase;
    float*          csum   = (float*)pObase;
    size_t full_need = 262144 + 8192 + 65536 + 327680 + 163840 + (size_t)BH*NT*NS*EE*2; // 6.07 MB

    k_spars<<<BH*LL/4, 256, 0, stream>>>(q, k, samp, spars);
    k_topk <<<BH,      256, 0, stream>>>(spars, topidx, sel);
    if (ws_size >= full_need) {
        k_attn_split<<<BH*NS, 256, 0, stream>>>(q, k, v, topidx, pm, pl, pO);
        k_attn_comb <<<BH*NT/4, 256, 0, stream>>>(pm, pl, pO, upd);
    } else {
        k_attn_old<<<BH*NT, 256, 0, stream>>>(q, k, v, topidx, upd);
    }
    k_csum<<<BH*NCH/4, 256, 0, stream>>>(v, csum);
    k_pfx <<<BH,       256, 0, stream>>>(csum);
    k_out <<<BH*NCH/4, 256, 0, stream>>>(v, csum, sel, upd, out);
}